// Round 1
// baseline (1886.672 us; speedup 1.0000x reference)
//
#include <hip/hip_runtime.h>
#include <hip/hip_bf16.h>
#include <cstdint>
#include <cstddef>

typedef __bf16 bf16;
typedef __attribute__((ext_vector_type(8))) __bf16 bf16x8;
typedef __attribute__((ext_vector_type(4))) float f32x4;

// ---------------------------------------------------------------------------
// conv1 (3x3, 3->16, VALID) + ReLU + maxpool 2x2 : x(16,512,512,3) -> (16,255,255,16)
// ---------------------------------------------------------------------------
__global__ __launch_bounds__(256) void conv1_pool(const float* __restrict__ x,
    const float* __restrict__ w, const float* __restrict__ bias,
    float* __restrict__ out) {
  __shared__ float ws[432];
  __shared__ float bs[16];
  int t = threadIdx.x;
  for (int i = t; i < 432; i += 256) ws[i] = w[i];
  if (t < 16) bs[t] = bias[t];
  __syncthreads();
  int idx = blockIdx.x * 256 + t;
  if (idx >= 16 * 255 * 255) return;
  int xo = idx % 255; int tmp = idx / 255; int yo = tmp % 255; int b = tmp / 255;
  float best[16];
#pragma unroll
  for (int c = 0; c < 16; c++) best[c] = 0.f;  // relu floor
#pragma unroll
  for (int py = 0; py < 2; py++)
#pragma unroll
  for (int px = 0; px < 2; px++) {
    float acc[16];
#pragma unroll
    for (int c = 0; c < 16; c++) acc[c] = bs[c];
    int iy0 = yo * 2 + py, ix0 = xo * 2 + px;
    for (int ky = 0; ky < 3; ky++)
    for (int kx = 0; kx < 3; kx++) {
      const float* xp = x + ((size_t)(b * 512 + iy0 + ky) * 512 + (ix0 + kx)) * 3;
      float v0 = xp[0], v1 = xp[1], v2 = xp[2];
      const float* wp = &ws[((ky * 3 + kx) * 3) * 16];
#pragma unroll
      for (int c = 0; c < 16; c++) acc[c] = fmaf(v0, wp[c], acc[c]);
#pragma unroll
      for (int c = 0; c < 16; c++) acc[c] = fmaf(v1, wp[16 + c], acc[c]);
#pragma unroll
      for (int c = 0; c < 16; c++) acc[c] = fmaf(v2, wp[32 + c], acc[c]);
    }
#pragma unroll
    for (int c = 0; c < 16; c++) best[c] = fmaxf(best[c], acc[c]);
  }
  float* op = out + (size_t)idx * 16;
#pragma unroll
  for (int c = 0; c < 16; c++) op[c] = best[c];
}

// ---------------------------------------------------------------------------
// conv2 (3x3, 16->16, VALID) + ReLU + maxpool + pad(1) + patch-extract
// in (16,255,255,16) -> patches bf16 (1024 rows, 4096 cols)
// padded coord (yp,xp) in [0,128); border cells are the SAME-pad zeros.
// patch row = b*64 + ty*8 + tx ; col = iy*256 + ix*16 + c
// ---------------------------------------------------------------------------
__global__ __launch_bounds__(256) void conv2_pool_patch(const float* __restrict__ in,
    const float* __restrict__ w, const float* __restrict__ bias,
    bf16* __restrict__ patches) {
  __shared__ float ws[2304];
  __shared__ float bs[16];
  int t = threadIdx.x;
  for (int i = t; i < 2304; i += 256) ws[i] = w[i];
  if (t < 16) bs[t] = bias[t];
  __syncthreads();
  int idx = blockIdx.x * 256 + t;            // 16*128*128 = 262144 exact
  int xp = idx & 127; int tmp = idx >> 7; int yp = tmp & 127; int b = tmp >> 7;
  int ty = yp >> 4, iy = yp & 15, tx = xp >> 4, ix = xp & 15;
  bf16* op = patches + ((size_t)(b * 64 + ty * 8 + tx) * 4096 + iy * 256 + ix * 16);
  if (yp == 0 || yp == 127 || xp == 0 || xp == 127) {
#pragma unroll
    for (int c = 0; c < 16; c++) op[c] = (bf16)0.f;
    return;
  }
  int y = yp - 1, x = xp - 1;                // pool2 output coord, [0,126)
  float best[16];
#pragma unroll
  for (int c = 0; c < 16; c++) best[c] = 0.f;
  for (int py = 0; py < 2; py++)
  for (int px = 0; px < 2; px++) {
    float acc[16];
#pragma unroll
    for (int c = 0; c < 16; c++) acc[c] = bs[c];
    int cy = y * 2 + py, cx = x * 2 + px;
    for (int ky = 0; ky < 3; ky++)
    for (int kx = 0; kx < 3; kx++) {
      const float* ip = in + ((size_t)(b * 255 + cy + ky) * 255 + (cx + kx)) * 16;
      const float* wp = &ws[(ky * 3 + kx) * 256];
      alignas(16) float v[16];
      *(float4*)&v[0]  = *(const float4*)(ip);
      *(float4*)&v[4]  = *(const float4*)(ip + 4);
      *(float4*)&v[8]  = *(const float4*)(ip + 8);
      *(float4*)&v[12] = *(const float4*)(ip + 12);
#pragma unroll
      for (int ci = 0; ci < 16; ci++) {
#pragma unroll
        for (int c = 0; c < 16; c++) acc[c] = fmaf(v[ci], wp[ci * 16 + c], acc[c]);
      }
    }
#pragma unroll
    for (int c = 0; c < 16; c++) best[c] = fmaxf(best[c], acc[c]);
  }
#pragma unroll
  for (int c = 0; c < 16; c++) op[c] = (bf16)best[c];
}

// ---------------------------------------------------------------------------
// bf16 MFMA GEMM: C(MxN) = A(MxK bf16) @ B(KxN fp32->bf16) + bias
// Block tile 64x64, BK=64, 4 waves in 2x2, wave tile 32x32 (2x2 of 16x16x32).
// MODE 0: C fp32 ; MODE 1: C bf16 = relu ; MODE 2: C fp32 + bf16 copy
// M is always 1024 (grid.y=16); M,N,K multiples of 64 -> no bounds checks.
// ---------------------------------------------------------------------------
#define GBK 64
#define LSTR 72   // padded LDS row stride (bf16 elems): 144 B, 16B-aligned, bank-spread

template<int MODE>
__device__ __forceinline__ void gemm_body(const bf16* __restrict__ A,
    const float* __restrict__ B, const float* __restrict__ bias,
    float* __restrict__ Cf, bf16* __restrict__ Cb,
    int bm, int bn, int N, int K) {
  __shared__ alignas(16) bf16 As[64 * LSTR];   // [m][k]
  __shared__ alignas(16) bf16 Bs[64 * LSTR];   // [n][k] (transposed tile)
  int t = threadIdx.x;
  int lane = t & 63, wave = t >> 6;
  int wm = (wave >> 1) * 32, wn = (wave & 1) * 32;
  int lq = lane >> 4, lr = lane & 15;
  f32x4 acc[2][2];
#pragma unroll
  for (int i = 0; i < 2; i++)
#pragma unroll
  for (int j = 0; j < 2; j++) acc[i][j] = (f32x4){0.f, 0.f, 0.f, 0.f};

  int am = t >> 2, akq = t & 3;      // A staging: row am, 16-elem k-chunk akq
  int bnl = t >> 2, bkc = t & 3;     // B staging: col bnl, 16-row k-chunk bkc
  const bf16* Ap = A + (size_t)(bm + am) * K + akq * 16;
  const float* Bp = B + (size_t)(bkc * 16) * N + bn + bnl;
  bf16* AsW = &As[am * LSTR + akq * 16];
  bf16* BsW = &Bs[bnl * LSTR + bkc * 16];

  for (int k0 = 0; k0 < K; k0 += GBK) {
    uint4 a0 = *(const uint4*)Ap;
    uint4 a1 = *(const uint4*)(Ap + 8);
    alignas(16) bf16 bvv[16];
    const float* bp = Bp;
#pragma unroll
    for (int i = 0; i < 16; i++) { bvv[i] = (bf16)(*bp); bp += N; }
    *(uint4*)AsW = a0;
    *(uint4*)(AsW + 8) = a1;
    *(uint4*)BsW = *(uint4*)&bvv[0];
    *(uint4*)(BsW + 8) = *(uint4*)&bvv[8];
    __syncthreads();
#pragma unroll
    for (int ks = 0; ks < 2; ks++) {
      bf16x8 af0 = *(const bf16x8*)&As[(wm + lr) * LSTR + ks * 32 + lq * 8];
      bf16x8 af1 = *(const bf16x8*)&As[(wm + 16 + lr) * LSTR + ks * 32 + lq * 8];
      bf16x8 bf0 = *(const bf16x8*)&Bs[(wn + lr) * LSTR + ks * 32 + lq * 8];
      bf16x8 bf1 = *(const bf16x8*)&Bs[(wn + 16 + lr) * LSTR + ks * 32 + lq * 8];
      acc[0][0] = __builtin_amdgcn_mfma_f32_16x16x32_bf16(af0, bf0, acc[0][0], 0, 0, 0);
      acc[0][1] = __builtin_amdgcn_mfma_f32_16x16x32_bf16(af0, bf1, acc[0][1], 0, 0, 0);
      acc[1][0] = __builtin_amdgcn_mfma_f32_16x16x32_bf16(af1, bf0, acc[1][0], 0, 0, 0);
      acc[1][1] = __builtin_amdgcn_mfma_f32_16x16x32_bf16(af1, bf1, acc[1][1], 0, 0, 0);
    }
    __syncthreads();
    Ap += GBK;
    Bp += (size_t)GBK * N;
  }
#pragma unroll
  for (int mi = 0; mi < 2; mi++)
#pragma unroll
  for (int ni = 0; ni < 2; ni++) {
    int col = bn + wn + ni * 16 + lr;
    float bb = bias[col];
#pragma unroll
    for (int r = 0; r < 4; r++) {
      int row = bm + wm + mi * 16 + lq * 4 + r;    // m89-verified C/D layout
      float v = acc[mi][ni][r] + bb;
      if (MODE == 1) {
        v = fmaxf(v, 0.f);
        Cb[(size_t)row * N + col] = (bf16)v;
      } else {
        Cf[(size_t)row * N + col] = v;
        if (MODE == 2) Cb[(size_t)row * N + col] = (bf16)v;
      }
    }
  }
}

template<int MODE>
__global__ __launch_bounds__(256) void gemm_one(const bf16* __restrict__ A,
    const float* __restrict__ B, const float* __restrict__ bias,
    float* __restrict__ Cf, bf16* __restrict__ Cb, int N, int K) {
  gemm_body<MODE>(A, B, bias, Cf, Cb, blockIdx.y * 64, blockIdx.x * 64, N, K);
}

__global__ __launch_bounds__(256) void gemm_qkv(const bf16* __restrict__ A,
    const float* __restrict__ Bq, const float* __restrict__ Bk, const float* __restrict__ Bv,
    const float* __restrict__ biq, const float* __restrict__ bik, const float* __restrict__ biv,
    float* __restrict__ q, float* __restrict__ k, float* __restrict__ v, int K) {
  int sel = blockIdx.x / 12;
  int bn = (blockIdx.x % 12) * 64;
  const float* B = (sel == 0) ? Bq : (sel == 1) ? Bk : Bv;
  const float* bias = (sel == 0) ? biq : (sel == 1) ? bik : biv;
  float* C = (sel == 0) ? q : (sel == 1) ? k : v;
  gemm_body<0>(A, B, bias, C, nullptr, blockIdx.y * 64, bn, 768, K);
}

// ---------------------------------------------------------------------------
// attention: one block per (b,h). q,k,v fp32 (1024,768) with head slice h*64.
// scores = q k^T / 8 ; softmax rows ; out = P v, written to (B,H,S,D)-flat bf16
// (matches the reference's reshape-without-transpose quirk).
// ---------------------------------------------------------------------------
__global__ __launch_bounds__(256) void attn_kernel(const float* __restrict__ Q,
    const float* __restrict__ Kf, const float* __restrict__ V, bf16* __restrict__ Aout) {
  __shared__ alignas(16) float qs[64 * 68];   // later reused as V^T [d][s]
  __shared__ alignas(16) float ks[64 * 68];
  __shared__ alignas(16) float ss[64 * 68];
  int t = threadIdx.x;
  int bh = blockIdx.x; int b = bh / 12, h = bh % 12;
  const float* qb = Q + (size_t)b * 49152 + h * 64;
  const float* kb = Kf + (size_t)b * 49152 + h * 64;
  const float* vb = V + (size_t)b * 49152 + h * 64;
  {
    int s = t >> 2, qd = (t & 3) * 16;
#pragma unroll
    for (int j = 0; j < 16; j += 4) {
      *(float4*)&qs[s * 68 + qd + j] = *(const float4*)(qb + (size_t)s * 768 + qd + j);
      *(float4*)&ks[s * 68 + qd + j] = *(const float4*)(kb + (size_t)s * 768 + qd + j);
    }
  }
  __syncthreads();
  int r = t >> 4, c = t & 15;   // thread owns (r+16i, c+16j)
  {
    float sc[4][4];
#pragma unroll
    for (int i = 0; i < 4; i++)
#pragma unroll
    for (int j = 0; j < 4; j++) sc[i][j] = 0.f;
    for (int k = 0; k < 64; k += 4) {
      float4 qv[4], kv[4];
#pragma unroll
      for (int i = 0; i < 4; i++) qv[i] = *(const float4*)&qs[(r + 16 * i) * 68 + k];
#pragma unroll
      for (int j = 0; j < 4; j++) kv[j] = *(const float4*)&ks[(c + 16 * j) * 68 + k];
#pragma unroll
      for (int i = 0; i < 4; i++)
#pragma unroll
      for (int j = 0; j < 4; j++)
        sc[i][j] += qv[i].x * kv[j].x + qv[i].y * kv[j].y + qv[i].z * kv[j].z + qv[i].w * kv[j].w;
    }
#pragma unroll
    for (int i = 0; i < 4; i++)
#pragma unroll
    for (int j = 0; j < 4; j++)
      ss[(r + 16 * i) * 68 + c + 16 * j] = sc[i][j] * 0.125f;
  }
  __syncthreads();
  {  // load V transposed into qs: qs[d][s] = V[s][d]
    int d = t & 63, s0 = (t >> 6) * 16;
    alignas(16) float vv[16];
#pragma unroll
    for (int i = 0; i < 16; i++) vv[i] = vb[(size_t)(s0 + i) * 768 + d];
#pragma unroll
    for (int i = 0; i < 16; i += 4) *(float4*)&qs[d * 68 + s0 + i] = *(float4*)&vv[i];
  }
  {  // softmax: wave handles 16 rows, lane = column
    int lane = t & 63, wave = t >> 6;
    for (int rr = 0; rr < 16; rr++) {
      int row = wave * 16 + rr;
      float v = ss[row * 68 + lane];
      float m = v;
#pragma unroll
      for (int off = 32; off > 0; off >>= 1) m = fmaxf(m, __shfl_xor(m, off));
      float e = __expf(v - m);
      float ssum = e;
#pragma unroll
      for (int off = 32; off > 0; off >>= 1) ssum += __shfl_xor(ssum, off);
      ss[row * 68 + lane] = e / ssum;
    }
  }
  __syncthreads();
  {
    float oc[4][4];
#pragma unroll
    for (int i = 0; i < 4; i++)
#pragma unroll
    for (int j = 0; j < 4; j++) oc[i][j] = 0.f;
    for (int k = 0; k < 64; k += 4) {
      float4 pv[4], vv[4];
#pragma unroll
      for (int i = 0; i < 4; i++) pv[i] = *(const float4*)&ss[(r + 16 * i) * 68 + k];
#pragma unroll
      for (int j = 0; j < 4; j++) vv[j] = *(const float4*)&qs[(c + 16 * j) * 68 + k];
#pragma unroll
      for (int i = 0; i < 4; i++)
#pragma unroll
      for (int j = 0; j < 4; j++)
        oc[i][j] += pv[i].x * vv[j].x + pv[i].y * vv[j].y + pv[i].z * vv[j].z + pv[i].w * vv[j].w;
    }
    bf16* ob = Aout + (size_t)b * 49152 + h * 4096;
#pragma unroll
    for (int i = 0; i < 4; i++)
#pragma unroll
    for (int j = 0; j < 4; j++)
      ob[(r + 16 * i) * 64 + c + 16 * j] = (bf16)oc[i][j];
  }
}

// ---------------------------------------------------------------------------
// fused residual-add + LayerNorm; writes fp32 and bf16 copies
// ---------------------------------------------------------------------------
__global__ __launch_bounds__(256) void ln_kernel(const float* __restrict__ X,
    const float* __restrict__ Y, const float* __restrict__ g, const float* __restrict__ bta,
    float* __restrict__ Of, bf16* __restrict__ Ob) {
  int row = blockIdx.x, t = threadIdx.x;
  const float* xp = X + (size_t)row * 768;
  const float* yp = Y + (size_t)row * 768;
  float vals[3]; float s = 0.f, s2 = 0.f;
#pragma unroll
  for (int i = 0; i < 3; i++) {
    float v = xp[t + 256 * i] + yp[t + 256 * i];
    vals[i] = v; s += v; s2 = fmaf(v, v, s2);
  }
#pragma unroll
  for (int off = 32; off > 0; off >>= 1) { s += __shfl_xor(s, off); s2 += __shfl_xor(s2, off); }
  __shared__ float rs[4], rs2[4];
  if ((t & 63) == 0) { rs[t >> 6] = s; rs2[t >> 6] = s2; }
  __syncthreads();
  s = rs[0] + rs[1] + rs[2] + rs[3];
  s2 = rs2[0] + rs2[1] + rs2[2] + rs2[3];
  float mean = s * (1.f / 768.f);
  float var = s2 * (1.f / 768.f) - mean * mean;   // biased var, as jnp.var
  float rstd = rsqrtf(var + 1e-6f);
  float* ofp = Of + (size_t)row * 768;
  bf16* obp = Ob + (size_t)row * 768;
#pragma unroll
  for (int i = 0; i < 3; i++) {
    int e = t + 256 * i;
    float o = (vals[i] - mean) * rstd * g[e] + bta[e];
    ofp[e] = o; obp[e] = (bf16)o;
  }
}

// ---------------------------------------------------------------------------
// mean-pool over seq + head matmul + sigmoid : one block per batch element
// ---------------------------------------------------------------------------
__global__ __launch_bounds__(256) void head_kernel(const float* __restrict__ T,
    const float* __restrict__ hw, const float* __restrict__ hbp, float* __restrict__ out) {
  int b = blockIdx.x, t = threadIdx.x;
  float acc = 0.f;
#pragma unroll
  for (int i = 0; i < 3; i++) {
    int e = t + 256 * i;
    float s = 0.f;
    for (int si = 0; si < 64; si++) s += T[(size_t)(b * 64 + si) * 768 + e];
    acc = fmaf(s * (1.f / 64.f), hw[e], acc);
  }
#pragma unroll
  for (int off = 32; off > 0; off >>= 1) acc += __shfl_xor(acc, off);
  __shared__ float rs[4];
  if ((t & 63) == 0) rs[t >> 6] = acc;
  __syncthreads();
  if (t == 0) {
    float z = rs[0] + rs[1] + rs[2] + rs[3] + hbp[0];
    out[b] = 1.f / (1.f + expf(-z));
  }
}

// ---------------------------------------------------------------------------
extern "C" void kernel_launch(void* const* d_in, const int* in_sizes, int n_in,
                              void* d_out, int out_size, void* d_ws, size_t ws_size,
                              hipStream_t stream) {
  const float* x     = (const float*)d_in[0];
  const float* c1w   = (const float*)d_in[1];
  const float* c1b   = (const float*)d_in[2];
  const float* c2w   = (const float*)d_in[3];
  const float* c2b   = (const float*)d_in[4];
  const float* projw = (const float*)d_in[5];
  const float* projb = (const float*)d_in[6];
  const float* Wq    = (const float*)d_in[7];
  const float* bq    = (const float*)d_in[8];
  const float* Wk    = (const float*)d_in[9];
  const float* bk    = (const float*)d_in[10];
  const float* Wv    = (const float*)d_in[11];
  const float* bv    = (const float*)d_in[12];
  const float* Wo    = (const float*)d_in[13];
  const float* bo    = (const float*)d_in[14];
  const float* W1    = (const float*)d_in[15];
  const float* b1    = (const float*)d_in[16];
  const float* W2    = (const float*)d_in[17];
  const float* b2    = (const float*)d_in[18];
  const float* ln1g  = (const float*)d_in[19];
  const float* ln1b  = (const float*)d_in[20];
  const float* ln2g  = (const float*)d_in[21];
  const float* ln2b  = (const float*)d_in[22];
  const float* headw = (const float*)d_in[23];
  const float* headb = (const float*)d_in[24];
  float* out = (float*)d_out;

  char* wp = (char*)d_ws;
  auto alloc = [&](size_t bytes) { char* p = wp; wp += (bytes + 255) & ~(size_t)255; return p; };
  float* c1p    = (float*)alloc((size_t)16 * 255 * 255 * 16 * 4);   // 66.6 MB
  bf16* patches = (bf16*)alloc((size_t)1024 * 4096 * 2);            // 8.4 MB
  float* tf     = (float*)alloc((size_t)1024 * 768 * 4);
  bf16*  tb     = (bf16*)alloc((size_t)1024 * 768 * 2);
  float* qf     = (float*)alloc((size_t)1024 * 768 * 4);            // also attn-proj out
  float* kf     = (float*)alloc((size_t)1024 * 768 * 4);            // also mlp out
  float* vf     = (float*)alloc((size_t)1024 * 768 * 4);
  bf16*  ab     = (bf16*)alloc((size_t)1024 * 768 * 2);
  float* o1f    = (float*)alloc((size_t)1024 * 768 * 4);
  bf16*  o1b    = (bf16*)alloc((size_t)1024 * 768 * 2);
  bf16*  hbuf   = (bf16*)alloc((size_t)1024 * 3072 * 2);            // MLP hidden

  conv1_pool<<<4065, 256, 0, stream>>>(x, c1w, c1b, c1p);
  conv2_pool_patch<<<1024, 256, 0, stream>>>(c1p, c2w, c2b, patches);
  gemm_one<2><<<dim3(12, 16), 256, 0, stream>>>(patches, projw, projb, tf, tb, 768, 4096);

  for (int i = 0; i < 8; i++) {
    const float* wq = Wq + (size_t)i * 589824;
    const float* wk = Wk + (size_t)i * 589824;
    const float* wv = Wv + (size_t)i * 589824;
    gemm_qkv<<<dim3(36, 16), 256, 0, stream>>>(tb, wq, wk, wv,
        bq + i * 768, bk + i * 768, bv + i * 768, qf, kf, vf, 768);
    attn_kernel<<<192, 256, 0, stream>>>(qf, kf, vf, ab);
    gemm_one<0><<<dim3(12, 16), 256, 0, stream>>>(ab, Wo + (size_t)i * 589824,
        bo + i * 768, qf, nullptr, 768, 768);
    ln_kernel<<<1024, 256, 0, stream>>>(tf, qf, ln1g + i * 768, ln1b + i * 768, o1f, o1b);
    gemm_one<1><<<dim3(48, 16), 256, 0, stream>>>(o1b, W1 + (size_t)i * 2359296,
        b1 + i * 3072, nullptr, hbuf, 3072, 768);
    gemm_one<0><<<dim3(12, 16), 256, 0, stream>>>(hbuf, W2 + (size_t)i * 2359296,
        b2 + i * 768, kf, nullptr, 768, 3072);
    ln_kernel<<<1024, 256, 0, stream>>>(o1f, kf, ln2g + i * 768, ln2b + i * 768, tf, tb);
  }
  head_kernel<<<16, 256, 0, stream>>>(tf, headw, headb, out);
}

// Round 2
// 1132.333 us; speedup vs baseline: 1.6662x; 1.6662x over previous
//
#include <hip/hip_runtime.h>
#include <hip/hip_bf16.h>
#include <cstdint>
#include <cstddef>

typedef __bf16 bf16;
typedef __attribute__((ext_vector_type(8))) __bf16 bf16x8;
typedef __attribute__((ext_vector_type(4))) float f32x4;

// ---------------------------------------------------------------------------
// weight transpose+cast: src (L,K,N) fp32 -> dst (L,N,K) bf16. grid(N/32,K/32,L)
// ---------------------------------------------------------------------------
__global__ __launch_bounds__(256) void wtrans(const float* __restrict__ src,
    bf16* __restrict__ dst, int K, int N) {
  __shared__ float tile[32][33];
  int l = blockIdx.z;
  src += (size_t)l * K * N; dst += (size_t)l * K * N;
  int n0 = blockIdx.x * 32, k0 = blockIdx.y * 32;
  int tx = threadIdx.x & 31, ty = threadIdx.x >> 5;
#pragma unroll
  for (int i = 0; i < 4; i++) {
    int k = ty + i * 8;
    tile[k][tx] = src[(size_t)(k0 + k) * N + n0 + tx];
  }
  __syncthreads();
#pragma unroll
  for (int i = 0; i < 4; i++) {
    int n = ty + i * 8;
    dst[(size_t)(n0 + n) * K + k0 + tx] = (bf16)tile[tx][n];
  }
}

// ---------------------------------------------------------------------------
// conv1 (3x3, 3->16, VALID) + ReLU + maxpool 2x2 : (16,512,512,3) -> bf16 (16,255,255,16)
// ---------------------------------------------------------------------------
__global__ __launch_bounds__(256) void conv1_pool(const float* __restrict__ x,
    const float* __restrict__ w, const float* __restrict__ bias,
    bf16* __restrict__ out) {
  __shared__ float ws[432];
  __shared__ float bs[16];
  int t = threadIdx.x;
  for (int i = t; i < 432; i += 256) ws[i] = w[i];
  if (t < 16) bs[t] = bias[t];
  __syncthreads();
  int idx = blockIdx.x * 256 + t;
  if (idx >= 16 * 255 * 255) return;
  int xo = idx % 255; int tmp = idx / 255; int yo = tmp % 255; int b = tmp / 255;
  float best[16];
#pragma unroll
  for (int c = 0; c < 16; c++) best[c] = 0.f;  // relu floor
#pragma unroll
  for (int py = 0; py < 2; py++)
#pragma unroll
  for (int px = 0; px < 2; px++) {
    float acc[16];
#pragma unroll
    for (int c = 0; c < 16; c++) acc[c] = bs[c];
    int iy0 = yo * 2 + py, ix0 = xo * 2 + px;
    for (int ky = 0; ky < 3; ky++)
    for (int kx = 0; kx < 3; kx++) {
      const float* xp = x + ((size_t)(b * 512 + iy0 + ky) * 512 + (ix0 + kx)) * 3;
      float v0 = xp[0], v1 = xp[1], v2 = xp[2];
      const float* wp = &ws[((ky * 3 + kx) * 3) * 16];
#pragma unroll
      for (int c = 0; c < 16; c++) acc[c] = fmaf(v0, wp[c], acc[c]);
#pragma unroll
      for (int c = 0; c < 16; c++) acc[c] = fmaf(v1, wp[16 + c], acc[c]);
#pragma unroll
      for (int c = 0; c < 16; c++) acc[c] = fmaf(v2, wp[32 + c], acc[c]);
    }
#pragma unroll
    for (int c = 0; c < 16; c++) best[c] = fmaxf(best[c], acc[c]);
  }
  bf16* op = out + (size_t)idx * 16;
#pragma unroll
  for (int c = 0; c < 16; c++) op[c] = (bf16)best[c];
}

// ---------------------------------------------------------------------------
// conv2 + ReLU + maxpool + pad(1) + patch-extract, LDS-staged per patch.
// in bf16 (16,255,255,16); block = one 16x16 patch; grid (8,8,16).
// LDS halo: 34x34 positions x 16ch, slot stride 20 bf16 (bank spread).
// ---------------------------------------------------------------------------
#define C2STR 20
__global__ __launch_bounds__(256) void conv2_pool_patch(const bf16* __restrict__ in,
    const float* __restrict__ w, const float* __restrict__ bias,
    bf16* __restrict__ patches) {
  __shared__ bf16 xs[34 * 34 * C2STR];   // 46240 B
  __shared__ float ws[2304];
  __shared__ float bs[16];
  int t = threadIdx.x;
  int tx = blockIdx.x, ty = blockIdx.y, b = blockIdx.z;
  for (int i = t; i < 2304; i += 256) ws[i] = w[i];
  if (t < 16) bs[t] = bias[t];
  int r0 = 32 * ty - 2, c0 = 32 * tx - 2;
  for (int i = t; i < 1156; i += 256) {
    int rr = i / 34, cc = i % 34;
    int gr = min(max(r0 + rr, 0), 254), gc = min(max(c0 + cc, 0), 254);
    const bf16* ip = in + ((size_t)(b * 255 + gr) * 255 + gc) * 16;
    uint4 v0 = *(const uint4*)ip;        // 8 bf16
    uint4 v1 = *(const uint4*)(ip + 8);
    bf16* op = &xs[i * C2STR];
    *(uint4*)op = v0;
    *(uint4*)(op + 8) = v1;
  }
  __syncthreads();
  int py_ = t >> 4, px_ = t & 15;
  int yp = ty * 16 + py_, xp = tx * 16 + px_;
  bf16* op = patches + ((size_t)(b * 64 + ty * 8 + tx) * 4096 + py_ * 256 + px_ * 16);
  if (yp == 0 || yp == 127 || xp == 0 || xp == 127) {
#pragma unroll
    for (int c = 0; c < 16; c++) op[c] = (bf16)0.f;
    return;
  }
  float best[16];
#pragma unroll
  for (int c = 0; c < 16; c++) best[c] = 0.f;
  for (int py = 0; py < 2; py++)
  for (int px = 0; px < 2; px++) {
    float acc[16];
#pragma unroll
    for (int c = 0; c < 16; c++) acc[c] = bs[c];
    for (int ky = 0; ky < 3; ky++)
    for (int kx = 0; kx < 3; kx++) {
      int lr_ = 2 * py_ + py + ky, lc_ = 2 * px_ + px + kx;
      const bf16* xpp = &xs[(lr_ * 34 + lc_) * C2STR];
      const float* wp = &ws[(ky * 3 + kx) * 256];
#pragma unroll
      for (int ci = 0; ci < 16; ci++) {
        float v = (float)xpp[ci];
#pragma unroll
        for (int c = 0; c < 16; c++) acc[c] = fmaf(v, wp[ci * 16 + c], acc[c]);
      }
    }
#pragma unroll
    for (int c = 0; c < 16; c++) best[c] = fmaxf(best[c], acc[c]);
  }
#pragma unroll
  for (int c = 0; c < 16; c++) op[c] = (bf16)best[c];
}

// ---------------------------------------------------------------------------
// bf16 MFMA GEMM: C = A(M,K) @ Bt(N,K)^T. 64x64 tile, BK=64, 4 waves 2x2,
// register-pipelined global prefetch. A,Bt bf16 K-major (16B vector staging).
// MODE 0: fp32 partial, no bias. MODE 1: bias+relu -> bf16.
// ---------------------------------------------------------------------------
#define LSTR 72

template<int MODE>
__device__ __forceinline__ void gemm_core(const bf16* __restrict__ A,
    const bf16* __restrict__ Bt, const float* __restrict__ bias,
    float* __restrict__ Cf, bf16* __restrict__ Cb,
    int bm, int bn, int N, int K, int k0, int kc) {
  __shared__ alignas(16) bf16 As[64 * LSTR];
  __shared__ alignas(16) bf16 Bs[64 * LSTR];
  int t = threadIdx.x, lane = t & 63, wave = t >> 6;
  int wm = (wave >> 1) * 32, wn = (wave & 1) * 32;
  int lq = lane >> 4, lr = lane & 15;
  f32x4 acc[2][2];
#pragma unroll
  for (int i = 0; i < 2; i++)
#pragma unroll
  for (int j = 0; j < 2; j++) acc[i][j] = (f32x4){0.f, 0.f, 0.f, 0.f};
  int r = t >> 2, c = (t & 3) * 16;
  const bf16* Ap = A + (size_t)(bm + r) * K + k0 + c;
  const bf16* Bp = Bt + (size_t)(bn + r) * K + k0 + c;
  bf16* AsW = &As[r * LSTR + c];
  bf16* BsW = &Bs[r * LSTR + c];
  uint4 a0 = *(const uint4*)Ap, a1 = *(const uint4*)(Ap + 8);
  uint4 b0 = *(const uint4*)Bp, b1 = *(const uint4*)(Bp + 8);
  for (int kk = 64; kk <= kc; kk += 64) {
    *(uint4*)AsW = a0; *(uint4*)(AsW + 8) = a1;
    *(uint4*)BsW = b0; *(uint4*)(BsW + 8) = b1;
    __syncthreads();
    if (kk < kc) {   // prefetch next K-tile while MFMA runs
      Ap += 64; Bp += 64;
      a0 = *(const uint4*)Ap; a1 = *(const uint4*)(Ap + 8);
      b0 = *(const uint4*)Bp; b1 = *(const uint4*)(Bp + 8);
    }
#pragma unroll
    for (int ks = 0; ks < 2; ks++) {
      bf16x8 af0 = *(const bf16x8*)&As[(wm + lr) * LSTR + ks * 32 + lq * 8];
      bf16x8 af1 = *(const bf16x8*)&As[(wm + 16 + lr) * LSTR + ks * 32 + lq * 8];
      bf16x8 bfr0 = *(const bf16x8*)&Bs[(wn + lr) * LSTR + ks * 32 + lq * 8];
      bf16x8 bfr1 = *(const bf16x8*)&Bs[(wn + 16 + lr) * LSTR + ks * 32 + lq * 8];
      acc[0][0] = __builtin_amdgcn_mfma_f32_16x16x32_bf16(af0, bfr0, acc[0][0], 0, 0, 0);
      acc[0][1] = __builtin_amdgcn_mfma_f32_16x16x32_bf16(af0, bfr1, acc[0][1], 0, 0, 0);
      acc[1][0] = __builtin_amdgcn_mfma_f32_16x16x32_bf16(af1, bfr0, acc[1][0], 0, 0, 0);
      acc[1][1] = __builtin_amdgcn_mfma_f32_16x16x32_bf16(af1, bfr1, acc[1][1], 0, 0, 0);
    }
    __syncthreads();
  }
#pragma unroll
  for (int mi = 0; mi < 2; mi++)
#pragma unroll
  for (int ni = 0; ni < 2; ni++) {
    int col = bn + wn + ni * 16 + lr;
#pragma unroll
    for (int rr = 0; rr < 4; rr++) {
      int row = bm + wm + mi * 16 + lq * 4 + rr;   // m89-verified C/D layout
      float v = acc[mi][ni][rr];
      if (MODE == 1) {
        v = fmaxf(v + bias[col], 0.f);
        Cb[(size_t)row * N + col] = (bf16)v;
      } else {
        Cf[(size_t)row * N + col] = v;
      }
    }
  }
}

template<int MODE>
__global__ __launch_bounds__(256) void gemm_std(const bf16* __restrict__ A,
    const bf16* __restrict__ Bt, const float* __restrict__ bias,
    float* __restrict__ Cf, bf16* __restrict__ Cb, int N, int K, int KC) {
  int s = blockIdx.z;
  float* Cfp = Cf ? Cf + (size_t)s * 1024 * N : nullptr;
  gemm_core<MODE>(A, Bt, bias, Cfp, Cb, blockIdx.y * 64, blockIdx.x * 64, N, K, s * KC, KC);
}

__global__ __launch_bounds__(256) void gemm_qkv(const bf16* __restrict__ A,
    const bf16* __restrict__ Btq, const bf16* __restrict__ Btk, const bf16* __restrict__ Btv,
    float* __restrict__ qp, float* __restrict__ kp, float* __restrict__ vp) {
  int z = blockIdx.z;               // 0..5 : sel*2 + split
  int sel = z >> 1, s = z & 1;
  const bf16* Bt = (sel == 0) ? Btq : (sel == 1) ? Btk : Btv;
  float* C = ((sel == 0) ? qp : (sel == 1) ? kp : vp) + (size_t)s * 786432;
  gemm_core<0>(A, Bt, nullptr, C, nullptr, blockIdx.y * 64, blockIdx.x * 64, 768, 768, s * 384, 384);
}

// ---------------------------------------------------------------------------
// attention: one block per (b,h). q,k,v are 2-way split-K fp32 partials
// (2,1024,768); bias added here. Output (B,H,S,D)-flat bf16 (reference quirk).
// ---------------------------------------------------------------------------
__global__ __launch_bounds__(256) void attn_kernel(const float* __restrict__ Qp,
    const float* __restrict__ Kp, const float* __restrict__ Vp,
    const float* __restrict__ bq, const float* __restrict__ bk, const float* __restrict__ bv,
    bf16* __restrict__ Aout) {
  __shared__ alignas(16) float qs[64 * 68];   // later reused as V^T [d][s]
  __shared__ alignas(16) float ks[64 * 68];
  __shared__ alignas(16) float ss[64 * 68];
  int t = threadIdx.x;
  int bh = blockIdx.x; int b = bh / 12, h = bh % 12;
  size_t base = (size_t)b * 49152 + h * 64;
  const float* qb0 = Qp + base; const float* qb1 = qb0 + 786432;
  const float* kb0 = Kp + base; const float* kb1 = kb0 + 786432;
  const float* vb0 = Vp + base; const float* vb1 = vb0 + 786432;
  {
    int s = t >> 2, qd = (t & 3) * 16;
#pragma unroll
    for (int j = 0; j < 16; j += 4) {
      float4 q0 = *(const float4*)(qb0 + (size_t)s * 768 + qd + j);
      float4 q1 = *(const float4*)(qb1 + (size_t)s * 768 + qd + j);
      float4 qb4 = *(const float4*)(bq + h * 64 + qd + j);
      float4 k0 = *(const float4*)(kb0 + (size_t)s * 768 + qd + j);
      float4 k1 = *(const float4*)(kb1 + (size_t)s * 768 + qd + j);
      float4 kb4 = *(const float4*)(bk + h * 64 + qd + j);
      qs[s * 68 + qd + j + 0] = q0.x + q1.x + qb4.x;
      qs[s * 68 + qd + j + 1] = q0.y + q1.y + qb4.y;
      qs[s * 68 + qd + j + 2] = q0.z + q1.z + qb4.z;
      qs[s * 68 + qd + j + 3] = q0.w + q1.w + qb4.w;
      ks[s * 68 + qd + j + 0] = k0.x + k1.x + kb4.x;
      ks[s * 68 + qd + j + 1] = k0.y + k1.y + kb4.y;
      ks[s * 68 + qd + j + 2] = k0.z + k1.z + kb4.z;
      ks[s * 68 + qd + j + 3] = k0.w + k1.w + kb4.w;
    }
  }
  __syncthreads();
  int r = t >> 4, c = t & 15;
  {
    float sc[4][4];
#pragma unroll
    for (int i = 0; i < 4; i++)
#pragma unroll
    for (int j = 0; j < 4; j++) sc[i][j] = 0.f;
    for (int k = 0; k < 64; k += 4) {
      float4 qv[4], kv[4];
#pragma unroll
      for (int i = 0; i < 4; i++) qv[i] = *(const float4*)&qs[(r + 16 * i) * 68 + k];
#pragma unroll
      for (int j = 0; j < 4; j++) kv[j] = *(const float4*)&ks[(c + 16 * j) * 68 + k];
#pragma unroll
      for (int i = 0; i < 4; i++)
#pragma unroll
      for (int j = 0; j < 4; j++)
        sc[i][j] += qv[i].x * kv[j].x + qv[i].y * kv[j].y + qv[i].z * kv[j].z + qv[i].w * kv[j].w;
    }
#pragma unroll
    for (int i = 0; i < 4; i++)
#pragma unroll
    for (int j = 0; j < 4; j++)
      ss[(r + 16 * i) * 68 + c + 16 * j] = sc[i][j] * 0.125f;
  }
  __syncthreads();
  {  // V^T into qs with partial-sum + bias
    int d = t & 63, s0 = (t >> 6) * 16;
    float bvd = bv[h * 64 + d];
    alignas(16) float vv[16];
#pragma unroll
    for (int i = 0; i < 16; i++)
      vv[i] = vb0[(size_t)(s0 + i) * 768 + d] + vb1[(size_t)(s0 + i) * 768 + d] + bvd;
#pragma unroll
    for (int i = 0; i < 16; i += 4) *(float4*)&qs[d * 68 + s0 + i] = *(float4*)&vv[i];
  }
  {  // softmax
    int lane = t & 63, wave = t >> 6;
    for (int rr = 0; rr < 16; rr++) {
      int row = wave * 16 + rr;
      float v = ss[row * 68 + lane];
      float m = v;
#pragma unroll
      for (int off = 32; off > 0; off >>= 1) m = fmaxf(m, __shfl_xor(m, off));
      float e = __expf(v - m);
      float ssum = e;
#pragma unroll
      for (int off = 32; off > 0; off >>= 1) ssum += __shfl_xor(ssum, off);
      ss[row * 68 + lane] = e / ssum;
    }
  }
  __syncthreads();
  {
    float oc[4][4];
#pragma unroll
    for (int i = 0; i < 4; i++)
#pragma unroll
    for (int j = 0; j < 4; j++) oc[i][j] = 0.f;
    for (int k = 0; k < 64; k += 4) {
      float4 pv[4], vv[4];
#pragma unroll
      for (int i = 0; i < 4; i++) pv[i] = *(const float4*)&ss[(r + 16 * i) * 68 + k];
#pragma unroll
      for (int j = 0; j < 4; j++) vv[j] = *(const float4*)&qs[(c + 16 * j) * 68 + k];
#pragma unroll
      for (int i = 0; i < 4; i++)
#pragma unroll
      for (int j = 0; j < 4; j++)
        oc[i][j] += pv[i].x * vv[j].x + pv[i].y * vv[j].y + pv[i].z * vv[j].z + pv[i].w * vv[j].w;
    }
    bf16* ob = Aout + (size_t)b * 49152 + h * 4096;
#pragma unroll
    for (int i = 0; i < 4; i++)
#pragma unroll
    for (int j = 0; j < 4; j++)
      ob[(r + 16 * i) * 64 + c + 16 * j] = (bf16)oc[i][j];
  }
}

// ---------------------------------------------------------------------------
// residual + S-way split-K partial sum + col bias + LayerNorm; fp32 + bf16 out
// ---------------------------------------------------------------------------
template<int S>
__global__ __launch_bounds__(256) void ln_kernel(const float* __restrict__ X,
    const float* __restrict__ Y, const float* __restrict__ yb,
    const float* __restrict__ g, const float* __restrict__ bta,
    float* __restrict__ Of, bf16* __restrict__ Ob) {
  int row = blockIdx.x, t = threadIdx.x;
  const float* xp = X + (size_t)row * 768;
  float vals[3]; float s = 0.f, s2 = 0.f;
#pragma unroll
  for (int i = 0; i < 3; i++) {
    int e = t + 256 * i;
    float v = xp[e] + yb[e];
#pragma unroll
    for (int p = 0; p < S; p++) v += Y[(size_t)p * 786432 + (size_t)row * 768 + e];
    vals[i] = v; s += v; s2 = fmaf(v, v, s2);
  }
#pragma unroll
  for (int off = 32; off > 0; off >>= 1) { s += __shfl_xor(s, off); s2 += __shfl_xor(s2, off); }
  __shared__ float rs[4], rs2[4];
  if ((t & 63) == 0) { rs[t >> 6] = s; rs2[t >> 6] = s2; }
  __syncthreads();
  s = rs[0] + rs[1] + rs[2] + rs[3];
  s2 = rs2[0] + rs2[1] + rs2[2] + rs2[3];
  float mean = s * (1.f / 768.f);
  float var = s2 * (1.f / 768.f) - mean * mean;
  float rstd = rsqrtf(var + 1e-6f);
  float* ofp = Of + (size_t)row * 768;
  bf16* obp = Ob + (size_t)row * 768;
#pragma unroll
  for (int i = 0; i < 3; i++) {
    int e = t + 256 * i;
    float o = (vals[i] - mean) * rstd * g[e] + bta[e];
    ofp[e] = o; obp[e] = (bf16)o;
  }
}

// proj 2-partial reduce + bias -> tf fp32 + tb bf16
__global__ __launch_bounds__(256) void reduce2(const float* __restrict__ P,
    const float* __restrict__ bias, float* __restrict__ Of, bf16* __restrict__ Ob) {
  int row = blockIdx.x, t = threadIdx.x;
#pragma unroll
  for (int i = 0; i < 3; i++) {
    int e = t + 256 * i;
    float v = P[(size_t)row * 768 + e] + P[786432 + (size_t)row * 768 + e] + bias[e];
    Of[(size_t)row * 768 + e] = v;
    Ob[(size_t)row * 768 + e] = (bf16)v;
  }
}

// ---------------------------------------------------------------------------
// mean-pool + head + sigmoid
// ---------------------------------------------------------------------------
__global__ __launch_bounds__(256) void head_kernel(const float* __restrict__ T,
    const float* __restrict__ hw, const float* __restrict__ hbp, float* __restrict__ out) {
  int b = blockIdx.x, t = threadIdx.x;
  float acc = 0.f;
#pragma unroll
  for (int i = 0; i < 3; i++) {
    int e = t + 256 * i;
    float s = 0.f;
    for (int si = 0; si < 64; si++) s += T[(size_t)(b * 64 + si) * 768 + e];
    acc = fmaf(s * (1.f / 64.f), hw[e], acc);
  }
#pragma unroll
  for (int off = 32; off > 0; off >>= 1) acc += __shfl_xor(acc, off);
  __shared__ float rs[4];
  if ((t & 63) == 0) rs[t >> 6] = acc;
  __syncthreads();
  if (t == 0) {
    float z = rs[0] + rs[1] + rs[2] + rs[3] + hbp[0];
    out[b] = 1.f / (1.f + expf(-z));
  }
}

// ---------------------------------------------------------------------------
extern "C" void kernel_launch(void* const* d_in, const int* in_sizes, int n_in,
                              void* d_out, int out_size, void* d_ws, size_t ws_size,
                              hipStream_t stream) {
  const float* x     = (const float*)d_in[0];
  const float* c1w   = (const float*)d_in[1];
  const float* c1b   = (const float*)d_in[2];
  const float* c2w   = (const float*)d_in[3];
  const float* c2b   = (const float*)d_in[4];
  const float* projw = (const float*)d_in[5];
  const float* projb = (const float*)d_in[6];
  const float* Wq    = (const float*)d_in[7];
  const float* bq    = (const float*)d_in[8];
  const float* Wk    = (const float*)d_in[9];
  const float* bk    = (const float*)d_in[10];
  const float* Wv    = (const float*)d_in[11];
  const float* bv    = (const float*)d_in[12];
  const float* Wo    = (const float*)d_in[13];
  const float* bo    = (const float*)d_in[14];
  const float* W1    = (const float*)d_in[15];
  const float* b1    = (const float*)d_in[16];
  const float* W2    = (const float*)d_in[17];
  const float* b2    = (const float*)d_in[18];
  const float* ln1g  = (const float*)d_in[19];
  const float* ln1b  = (const float*)d_in[20];
  const float* ln2g  = (const float*)d_in[21];
  const float* ln2b  = (const float*)d_in[22];
  const float* headw = (const float*)d_in[23];
  const float* headb = (const float*)d_in[24];
  float* out = (float*)d_out;

  char* wp = (char*)d_ws;
  auto alloc = [&](size_t bytes) { char* p = wp; wp += (bytes + 255) & ~(size_t)255; return p; };
  bf16* c1p     = (bf16*)alloc((size_t)16 * 255 * 255 * 16 * 2);   // 33.3 MB
  bf16* patches = (bf16*)alloc((size_t)1024 * 4096 * 2);           // 8.4 MB
  bf16* projT   = (bf16*)alloc((size_t)4096 * 768 * 2);
  bf16* WqT     = (bf16*)alloc((size_t)8 * 768 * 768 * 2);
  bf16* WkT     = (bf16*)alloc((size_t)8 * 768 * 768 * 2);
  bf16* WvT     = (bf16*)alloc((size_t)8 * 768 * 768 * 2);
  bf16* WoT     = (bf16*)alloc((size_t)8 * 768 * 768 * 2);
  bf16* W1T     = (bf16*)alloc((size_t)8 * 768 * 3072 * 2);
  bf16* W2T     = (bf16*)alloc((size_t)8 * 3072 * 768 * 2);
  float* pp     = (float*)alloc((size_t)2 * 1024 * 768 * 4);       // proj partials
  float* tf     = (float*)alloc((size_t)1024 * 768 * 4);
  bf16*  tb     = (bf16*)alloc((size_t)1024 * 768 * 2);
  float* qp     = (float*)alloc((size_t)2 * 1024 * 768 * 4);
  float* kp     = (float*)alloc((size_t)2 * 1024 * 768 * 4);
  float* vp     = (float*)alloc((size_t)2 * 1024 * 768 * 4);
  float* wop    = (float*)alloc((size_t)2 * 1024 * 768 * 4);
  float* w2p    = (float*)alloc((size_t)4 * 1024 * 768 * 4);
  bf16*  ab     = (bf16*)alloc((size_t)1024 * 768 * 2);
  float* o1f    = (float*)alloc((size_t)1024 * 768 * 4);
  bf16*  o1b    = (bf16*)alloc((size_t)1024 * 768 * 2);
  bf16*  hbuf   = (bf16*)alloc((size_t)1024 * 3072 * 2);

  // weight prep
  wtrans<<<dim3(24, 128, 1), 256, 0, stream>>>(projw, projT, 4096, 768);
  wtrans<<<dim3(24, 24, 8), 256, 0, stream>>>(Wq, WqT, 768, 768);
  wtrans<<<dim3(24, 24, 8), 256, 0, stream>>>(Wk, WkT, 768, 768);
  wtrans<<<dim3(24, 24, 8), 256, 0, stream>>>(Wv, WvT, 768, 768);
  wtrans<<<dim3(24, 24, 8), 256, 0, stream>>>(Wo, WoT, 768, 768);
  wtrans<<<dim3(96, 24, 8), 256, 0, stream>>>(W1, W1T, 768, 3072);
  wtrans<<<dim3(24, 96, 8), 256, 0, stream>>>(W2, W2T, 3072, 768);

  conv1_pool<<<4065, 256, 0, stream>>>(x, c1w, c1b, c1p);
  conv2_pool_patch<<<dim3(8, 8, 16), 256, 0, stream>>>(c1p, c2w, c2b, patches);
  gemm_std<0><<<dim3(12, 16, 2), 256, 0, stream>>>(patches, projT, nullptr, pp, nullptr, 768, 4096, 2048);
  reduce2<<<1024, 256, 0, stream>>>(pp, projb, tf, tb);

  for (int i = 0; i < 8; i++) {
    gemm_qkv<<<dim3(12, 16, 6), 256, 0, stream>>>(tb,
        WqT + (size_t)i * 589824, WkT + (size_t)i * 589824, WvT + (size_t)i * 589824,
        qp, kp, vp);
    attn_kernel<<<192, 256, 0, stream>>>(qp, kp, vp,
        bq + i * 768, bk + i * 768, bv + i * 768, ab);
    gemm_std<0><<<dim3(12, 16, 2), 256, 0, stream>>>(ab, WoT + (size_t)i * 589824,
        nullptr, wop, nullptr, 768, 768, 384);
    ln_kernel<2><<<1024, 256, 0, stream>>>(tf, wop, bo + i * 768,
        ln1g + i * 768, ln1b + i * 768, o1f, o1b);
    gemm_std<1><<<dim3(48, 16, 1), 256, 0, stream>>>(o1b, W1T + (size_t)i * 2359296,
        b1 + i * 3072, nullptr, hbuf, 3072, 768, 768);
    gemm_std<0><<<dim3(12, 16, 4), 256, 0, stream>>>(hbuf, W2T + (size_t)i * 2359296,
        nullptr, w2p, nullptr, 768, 3072, 768);
    ln_kernel<4><<<1024, 256, 0, stream>>>(o1f, w2p, b2 + i * 768,
        ln2g + i * 768, ln2b + i * 768, tf, tb);
  }
  head_kernel<<<16, 256, 0, stream>>>(tf, headw, headb, out);
}